// Round 11
// baseline (286.496 us; speedup 1.0000x reference)
//
#include <hip/hip_runtime.h>
#include <hip/hip_bf16.h>

// B=8, F=256, T=512, D=40, S=4
#define BATCHES 8
#define NROWS (256 * 512)                 // N = F*T = 131072
#define DE 40
#define SV 4
#define GP 48                             // Gram dim: 40 E + 4 V + 4 zero pad
#define NTILE 1536                        // 6 lower-tri 16x16 tiles per partial
#define ROWS_PER_BLOCK 512
#define CHUNKS (NROWS / ROWS_PER_BLOCK)   // 256 -> grid 2048, 6 blocks/CU (MLP probe)
#define RSTAGE 128                        // rows per stage (4 waves x K=32)
#define NSTAGES (ROWS_PER_BLOCK / RSTAGE) // 4
#define COLBYTES 256                      // RSTAGE * 2 B bf16, column-major
#define TILEBYTES (GP * COLBYTES)         // 12288 per buffer

typedef __attribute__((ext_vector_type(8))) short bf16x8;  // MFMA A/B frag
typedef __attribute__((ext_vector_type(4))) float f32x4;   // MFMA C/D frag
typedef __attribute__((ext_vector_type(2))) int i32x2;     // 4 bf16 packed
typedef __attribute__((ext_vector_type(4))) float f4v;     // clang-native float4

__device__ __forceinline__ int pk_bf16(float lo, float hi) {
    __hip_bfloat162 h2 = __float22bfloat162_rn(float2{lo, hi});  // RNE packed cvt
    return *reinterpret_cast<int*>(&h2);
}

__device__ __forceinline__ float4 ldnt(const float4* p) {
    // __builtin_nontemporal_load needs a clang-native vector type, not
    // HIP_vector_type<float,4> -- round-trip through ext_vector_type.
    f4v v = __builtin_nontemporal_load(reinterpret_cast<const f4v*>(p));
    return make_float4(v.x, v.y, v.z, v.w);
}

// T4 barrier: LDS-visibility only. hipcc's __syncthreads() drains vmcnt(0),
// which forces all in-flight global prefetches to land every stage; this
// barrier lets them stay outstanding (compiler still emits counted vmcnt(N)
// at the use sites in write_stage).
__device__ __forceinline__ void bar_lgkm() {
    asm volatile("s_waitcnt lgkmcnt(0)" ::: "memory");
    __builtin_amdgcn_s_barrier();
    asm volatile("" ::: "memory");
}

struct ARegs { float4 a0, a1, a2, a3; };

__global__ __launch_bounds__(256, 6) void gram_kernel(const float* __restrict__ E,
                                                      const float* __restrict__ V,
                                                      float* __restrict__ P,
                                                      float* __restrict__ out) {
    __shared__ __align__(16) char tb[2][TILEBYTES];

    const int tid = threadIdx.x;
    const int lane = tid & 63;
    const int wave = tid >> 6;            // K-chunk: rows 32*wave.. of stage
    const int b = blockIdx.x / CHUNKS;
    const int chunk = blockIdx.x % CHUNKS;
    const size_t row0 = (size_t)chunk * ROWS_PER_BLOCK;

    // zero the output accumulator in-kernel: removes the hipMemsetAsync
    // dispatch (stream ordering makes this visible to reduce_finish).
    if (blockIdx.x == 0 && tid == 0) out[0] = 0.f;

    const float4* __restrict__ Eg = (const float4*)(E + (size_t)b * NROWS * DE) + row0 * 10;
    const float4* __restrict__ Vg = (const float4*)(V + (size_t)b * NROWS * SV) + row0;

    if (tid < 128) {  // zero pad cols 44..47 of both buffers (constant all stages)
        const int bb = tid >> 6, off = (tid & 63) * 16;
        *(float4*)&tb[bb][44 * COLBYTES + off] = make_float4(0.f, 0.f, 0.f, 0.f);
    }

    // Slots: idx -> cg = idx%11 (0..9 E f4-col, 10 V), rg = idx/11 (rows 4rg..4rg+3).
    // Thread owns slot tid (A), plus slot tid+256 if tid<96 (B). 352 slots total.
    const int cgA = tid % 11, rgA = tid / 11;
    const int cgB = (tid + 256) % 11, rgB = (tid + 256) / 11;
    const bool hasB = (tid < 96);
    const bool vA = (cgA == 10), vB = (cgB == 10);
    const int pA = vA ? 1 : 10, cA = vA ? 0 : cgA;   // per-row f4 pitch, f4 col
    const int pB = vB ? 1 : 10, cB = vB ? 0 : cgB;
    const float4* __restrict__ gA = vA ? Vg : Eg;
    const float4* __restrict__ gB = vB ? Vg : Eg;
    const int oA = 4 * rgA * pA + cA;
    const int oB = 4 * rgB * pB + cB;

    f32x4 acc[6];  // lower-tri 16x16 tiles: (0,0)(1,0)(1,1)(2,0)(2,1)(2,2)
    #pragma unroll
    for (int i = 0; i < 6; ++i) acc[i] = (f32x4){0.f, 0.f, 0.f, 0.f};

    const int fcol = lane & 15;
    const int fq = lane >> 4;
    // Read-side swizzle offsets. Layout swizzle g(col) = (col + (col>>2)) & 15
    // = (5*cg + j) & 15 -- distinct mod 16 across cg (plain col&15 collapsed to
    // 2 bank-pairs per unrolled store -> ~5.5-way ds_write conflicts).
    // For fragment column col = 16c + fcol: g = (4c + fcol + (fcol>>2)) & 15.
    const int fo0 = (wave * 64 + fq * 16 + 16 * ((0 + fcol + (fcol >> 2)) & 15)) & 255;
    const int fo1 = (wave * 64 + fq * 16 + 16 * ((4 + fcol + (fcol >> 2)) & 15)) & 255;
    const int fo2 = (wave * 64 + fq * 16 + 16 * ((8 + fcol + (fcol >> 2)) & 15)) & 255;

    ARegs A[2];
    float4 b0, b1, b2, b3;

    auto load_a = [&](ARegs& r, int sidx) {
        const int adv = sidx * RSTAGE;
        r.a0 = ldnt(&gA[oA + adv * pA]);          r.a1 = ldnt(&gA[oA + adv * pA + pA]);
        r.a2 = ldnt(&gA[oA + adv * pA + 2 * pA]); r.a3 = ldnt(&gA[oA + adv * pA + 3 * pA]);
    };
    auto load_b = [&](int sidx) {
        if (!hasB) return;
        const int adv = sidx * RSTAGE;
        b0 = ldnt(&gB[oB + adv * pB]);          b1 = ldnt(&gB[oB + adv * pB + pB]);
        b2 = ldnt(&gB[oB + adv * pB + 2 * pB]); b3 = ldnt(&gB[oB + adv * pB + 3 * pB]);
    };
    auto write_stage = [&](const ARegs& r, int bufidx) {
        char* base = tb[bufidx];
        #pragma unroll
        for (int j = 0; j < 4; ++j) {
            const float f0 = (j == 0) ? r.a0.x : (j == 1) ? r.a0.y : (j == 2) ? r.a0.z : r.a0.w;
            const float f1 = (j == 0) ? r.a1.x : (j == 1) ? r.a1.y : (j == 2) ? r.a1.z : r.a1.w;
            const float f2 = (j == 0) ? r.a2.x : (j == 1) ? r.a2.y : (j == 2) ? r.a2.z : r.a2.w;
            const float f3 = (j == 0) ? r.a3.x : (j == 1) ? r.a3.y : (j == 2) ? r.a3.z : r.a3.w;
            const int col = 4 * cgA + j;
            const int off = (8 * rgA + 16 * ((5 * cgA + j) & 15)) & 255;
            i32x2 p = { pk_bf16(f0, f1), pk_bf16(f2, f3) };
            *(i32x2*)&base[col * COLBYTES + off] = p;
        }
        if (hasB) {
            #pragma unroll
            for (int j = 0; j < 4; ++j) {
                const float f0 = (j == 0) ? b0.x : (j == 1) ? b0.y : (j == 2) ? b0.z : b0.w;
                const float f1 = (j == 0) ? b1.x : (j == 1) ? b1.y : (j == 2) ? b1.z : b1.w;
                const float f2 = (j == 0) ? b2.x : (j == 1) ? b2.y : (j == 2) ? b2.z : b2.w;
                const float f3 = (j == 0) ? b3.x : (j == 1) ? b3.y : (j == 2) ? b3.z : b3.w;
                const int col = 4 * cgB + j;
                const int off = (8 * rgB + 16 * ((5 * cgB + j) & 15)) & 255;
                i32x2 p = { pk_bf16(f0, f1), pk_bf16(f2, f3) };
                *(i32x2*)&base[col * COLBYTES + off] = p;
            }
        }
    };

    // prologue: stage 0 staged; A stages 1,2 and B stage 1 in flight
    load_a(A[0], 0);
    load_b(0);
    load_a(A[1], 1);           // issue ahead of write_stage (independent regs)
    write_stage(A[0], 0);      // waits only its own loads (counted vmcnt)
    load_b(1);
    load_a(A[0], 2);           // A[0] free after write_stage(0)
    bar_lgkm();

    #pragma unroll
    for (int s = 0; s < NSTAGES; ++s) {
        {   // compute on buf s&1: 3 frag loads + 6 MFMAs (frag = both A and B operand)
            const char* base = tb[s & 1];
            const bf16x8 f0 = *(const bf16x8*)&base[(0 * 16 + fcol) * COLBYTES + fo0];
            const bf16x8 f1 = *(const bf16x8*)&base[(1 * 16 + fcol) * COLBYTES + fo1];
            const bf16x8 f2 = *(const bf16x8*)&base[(2 * 16 + fcol) * COLBYTES + fo2];
            acc[0] = __builtin_amdgcn_mfma_f32_16x16x32_bf16(f0, f0, acc[0], 0, 0, 0);
            acc[1] = __builtin_amdgcn_mfma_f32_16x16x32_bf16(f1, f0, acc[1], 0, 0, 0);
            acc[2] = __builtin_amdgcn_mfma_f32_16x16x32_bf16(f1, f1, acc[2], 0, 0, 0);
            acc[3] = __builtin_amdgcn_mfma_f32_16x16x32_bf16(f2, f0, acc[3], 0, 0, 0);
            acc[4] = __builtin_amdgcn_mfma_f32_16x16x32_bf16(f2, f1, acc[4], 0, 0, 0);
            acc[5] = __builtin_amdgcn_mfma_f32_16x16x32_bf16(f2, f2, acc[5], 0, 0, 0);
        }
        if (s + 1 < NSTAGES) write_stage(A[(s + 1) & 1], (s + 1) & 1);  // stage s+1 -> other buf
        if (s + 3 < NSTAGES) load_a(A[(s + 1) & 1], s + 3);             // refill freed A set
        if (s + 2 < NSTAGES) load_b(s + 2);
        bar_lgkm();  // LDS-only barrier: prefetch loads stay in flight
    }

    // single-barrier cross-wave merge: dump accs into tb scratch, one barrier,
    // then 1536 coalesced sums+stores (lower-tri tiles only).
    // C/D layout col=lane&15, row=(lane>>4)*4+reg [m89/m91].
    // part layout: [wave][t6][row 0..15][col 0..15] floats = 24576 B = sizeof(tb).
    float* part = (float*)tb;
    #pragma unroll
    for (int t6 = 0; t6 < 6; ++t6) {
        #pragma unroll
        for (int r = 0; r < 4; ++r)
            part[wave * NTILE + t6 * 256 + (fq * 4 + r) * 16 + fcol] = acc[t6][r];
    }
    bar_lgkm();

    // P[block][1536] identity-indexed: e = t6*256 + row*16 + col. Pure coalesced.
    float* __restrict__ Pb = P + (size_t)blockIdx.x * NTILE;
    #pragma unroll
    for (int i = 0; i < 6; ++i) {
        const int e = tid + 256 * i;
        Pb[e] = part[e] + part[NTILE + e] + part[2 * NTILE + e] + part[3 * NTILE + e];
    }
}

// Sum the 256 chunk-partials per (batch, tile-entry), apply mask, reduce to out[0].
// Grid: BATCHES * 24 = 192 blocks; block owns 64 entries, 4-way chunk split.
__global__ __launch_bounds__(256) void reduce_finish(const float* __restrict__ P,
                                                     float* __restrict__ out) {
    const int tid = threadIdx.x;
    const int b = blockIdx.x / 24;
    const int e0 = (blockIdx.x % 24) * 64;
    const int cs = tid / 64;            // chunk strip 0..3
    const int el = tid % 64;            // entry within strip
    const int e = e0 + el;              // 0..1535

    float g = 0.f;
    const float* base = P + (size_t)b * CHUNKS * NTILE + e;
    #pragma unroll 4
    for (int c = cs; c < CHUNKS; c += 4) g += base[(size_t)c * NTILE];  // 256B/wave coalesced

    __shared__ float part[4][64];
    part[cs][el] = g;
    __syncthreads();

    float contrib = 0.f;
    if (tid < 64) {
        g = part[0][el] + part[1][el] + part[2][el] + part[3][el];
        // e -> (t6, row, col) -> (gi, gj) in the 48x48 Gram
        const int t6 = e >> 8;
        const int t = (t6 >= 3) ? 2 : (t6 >= 1) ? 1 : 0;
        const int u = t6 - ((t * (t + 1)) >> 1);
        const int gi = 16 * t + ((e >> 4) & 15);
        const int gj = 16 * u + (e & 15);
        if (gi < (DE + SV) && gj <= gi) {
            const float w = (gi == gj) ? 1.f : 2.f;                   // off-diag counted twice
            const float sgn = ((gi < DE) == (gj < DE)) ? 1.f : -1.f;  // EE/VV +, mixed -
            contrib = w * sgn * g * g;
        }
        #pragma unroll
        for (int o = 32; o > 0; o >>= 1) contrib += __shfl_down(contrib, o, 64);
        if (tid == 0)
            atomicAdd(out, contrib * (1.f / ((float)BATCHES * (float)NROWS)));  // 192 atomics
    }
}

extern "C" void kernel_launch(void* const* d_in, const int* in_sizes, int n_in,
                              void* d_out, int out_size, void* d_ws, size_t ws_size,
                              hipStream_t stream) {
    const float* E = (const float*)d_in[0];   // embeddings (B,F,T,D) fp32
    const float* V = (const float*)d_in[1];   // assignments (B,F,T,S) fp32
    float* P = (float*)d_ws;                  // 2048 x 1536 fp32 partial tiles (12.6 MB)

    // no hipMemsetAsync: gram_kernel block 0 zeroes out[0] (stream-ordered
    // before reduce_finish's atomicAdds)
    gram_kernel<<<BATCHES * CHUNKS, 256, 0, stream>>>(E, V, P, (float*)d_out);
    reduce_finish<<<BATCHES * 24, 256, 0, stream>>>(P, (float*)d_out);
}

// Round 12
// 238.470 us; speedup vs baseline: 1.2014x; 1.2014x over previous
//
#include <hip/hip_runtime.h>
#include <hip/hip_bf16.h>

// B=8, F=256, T=512, D=40, S=4
#define BATCHES 8
#define NROWS (256 * 512)                 // N = F*T = 131072
#define DE 40
#define SV 4
#define GP 48                             // Gram dim: 40 E + 4 V + 4 zero pad
#define NTILE 1536                        // 6 lower-tri 16x16 tiles per partial
#define ROWS_PER_BLOCK 1024
#define CHUNKS (NROWS / ROWS_PER_BLOCK)   // 128 -> grid 1024, 4 blocks/CU (best measured)
#define RSTAGE 128                        // rows per stage (4 waves x K=32)
#define NSTAGES (ROWS_PER_BLOCK / RSTAGE) // 8
#define COLBYTES 256                      // RSTAGE * 2 B bf16, column-major
#define TILEBYTES (GP * COLBYTES)         // 12288 per buffer

typedef __attribute__((ext_vector_type(8))) short bf16x8;  // MFMA A/B frag
typedef __attribute__((ext_vector_type(4))) float f32x4;   // MFMA C/D frag
typedef __attribute__((ext_vector_type(2))) int i32x2;     // 4 bf16 packed
typedef __attribute__((ext_vector_type(4))) float f4v;     // clang-native float4

__device__ __forceinline__ int pk_bf16(float lo, float hi) {
    __hip_bfloat162 h2 = __float22bfloat162_rn(float2{lo, hi});  // RNE packed cvt
    return *reinterpret_cast<int*>(&h2);
}

__device__ __forceinline__ float4 ldnt(const float4* p) {
    // __builtin_nontemporal_load needs a clang-native vector type, not
    // HIP_vector_type<float,4> -- round-trip through ext_vector_type.
    f4v v = __builtin_nontemporal_load(reinterpret_cast<const f4v*>(p));
    return make_float4(v.x, v.y, v.z, v.w);
}

// T4 barrier: LDS-visibility only. hipcc's __syncthreads() drains vmcnt(0),
// which forces all in-flight global prefetches to land every stage; this
// barrier lets them stay outstanding (compiler still emits counted vmcnt(N)
// at the use sites in write_stage).
__device__ __forceinline__ void bar_lgkm() {
    asm volatile("s_waitcnt lgkmcnt(0)" ::: "memory");
    __builtin_amdgcn_s_barrier();
    asm volatile("" ::: "memory");
}

struct ARegs { float4 a0, a1, a2, a3; };

__global__ __launch_bounds__(256, 4) void gram_kernel(const float* __restrict__ E,
                                                      const float* __restrict__ V,
                                                      float* __restrict__ P,
                                                      float* __restrict__ out) {
    __shared__ __align__(16) char tb[2][TILEBYTES];

    const int tid = threadIdx.x;
    const int lane = tid & 63;
    const int wave = tid >> 6;            // K-chunk: rows 32*wave.. of stage
    const int b = blockIdx.x / CHUNKS;
    const int chunk = blockIdx.x % CHUNKS;
    const size_t row0 = (size_t)chunk * ROWS_PER_BLOCK;

    // zero the output accumulator in-kernel: removes the hipMemsetAsync
    // dispatch (stream ordering makes this visible to reduce_finish).
    if (blockIdx.x == 0 && tid == 0) out[0] = 0.f;

    const float4* __restrict__ Eg = (const float4*)(E + (size_t)b * NROWS * DE) + row0 * 10;
    const float4* __restrict__ Vg = (const float4*)(V + (size_t)b * NROWS * SV) + row0;

    if (tid < 128) {  // zero pad cols 44..47 of both buffers (constant all stages)
        const int bb = tid >> 6, off = (tid & 63) * 16;
        *(float4*)&tb[bb][44 * COLBYTES + off] = make_float4(0.f, 0.f, 0.f, 0.f);
    }

    // Slots: idx -> cg = idx%11 (0..9 E f4-col, 10 V), rg = idx/11 (rows 4rg..4rg+3).
    // Thread owns slot tid (A), plus slot tid+256 if tid<96 (B). 352 slots total.
    const int cgA = tid % 11, rgA = tid / 11;
    const int cgB = (tid + 256) % 11, rgB = (tid + 256) / 11;
    const bool hasB = (tid < 96);
    const bool vA = (cgA == 10), vB = (cgB == 10);
    const int pA = vA ? 1 : 10, cA = vA ? 0 : cgA;   // per-row f4 pitch, f4 col
    const int pB = vB ? 1 : 10, cB = vB ? 0 : cgB;
    const float4* __restrict__ gA = vA ? Vg : Eg;
    const float4* __restrict__ gB = vB ? Vg : Eg;
    const int oA = 4 * rgA * pA + cA;
    const int oB = 4 * rgB * pB + cB;

    f32x4 acc[6];  // lower-tri 16x16 tiles: (0,0)(1,0)(1,1)(2,0)(2,1)(2,2)
    #pragma unroll
    for (int i = 0; i < 6; ++i) acc[i] = (f32x4){0.f, 0.f, 0.f, 0.f};

    const int fcol = lane & 15;
    const int fq = lane >> 4;
    // Read-side swizzle offsets. Layout swizzle g(col) = (col + (col>>2)) & 15
    // = (5*cg + j) & 15 -- distinct mod 16 across cg (plain col&15 collapsed to
    // 2 bank-pairs per unrolled store -> ~5.5-way ds_write conflicts).
    // For fragment column col = 16c + fcol: g = (4c + fcol + (fcol>>2)) & 15.
    const int fo0 = (wave * 64 + fq * 16 + 16 * ((0 + fcol + (fcol >> 2)) & 15)) & 255;
    const int fo1 = (wave * 64 + fq * 16 + 16 * ((4 + fcol + (fcol >> 2)) & 15)) & 255;
    const int fo2 = (wave * 64 + fq * 16 + 16 * ((8 + fcol + (fcol >> 2)) & 15)) & 255;

    ARegs A[2];
    float4 b0, b1, b2, b3;

    auto load_a = [&](ARegs& r, int sidx) {
        const int adv = sidx * RSTAGE;
        r.a0 = ldnt(&gA[oA + adv * pA]);          r.a1 = ldnt(&gA[oA + adv * pA + pA]);
        r.a2 = ldnt(&gA[oA + adv * pA + 2 * pA]); r.a3 = ldnt(&gA[oA + adv * pA + 3 * pA]);
    };
    auto load_b = [&](int sidx) {
        if (!hasB) return;
        const int adv = sidx * RSTAGE;
        b0 = ldnt(&gB[oB + adv * pB]);          b1 = ldnt(&gB[oB + adv * pB + pB]);
        b2 = ldnt(&gB[oB + adv * pB + 2 * pB]); b3 = ldnt(&gB[oB + adv * pB + 3 * pB]);
    };
    auto write_stage = [&](const ARegs& r, int bufidx) {
        char* base = tb[bufidx];
        #pragma unroll
        for (int j = 0; j < 4; ++j) {
            const float f0 = (j == 0) ? r.a0.x : (j == 1) ? r.a0.y : (j == 2) ? r.a0.z : r.a0.w;
            const float f1 = (j == 0) ? r.a1.x : (j == 1) ? r.a1.y : (j == 2) ? r.a1.z : r.a1.w;
            const float f2 = (j == 0) ? r.a2.x : (j == 1) ? r.a2.y : (j == 2) ? r.a2.z : r.a2.w;
            const float f3 = (j == 0) ? r.a3.x : (j == 1) ? r.a3.y : (j == 2) ? r.a3.z : r.a3.w;
            const int col = 4 * cgA + j;
            const int off = (8 * rgA + 16 * ((5 * cgA + j) & 15)) & 255;
            i32x2 p = { pk_bf16(f0, f1), pk_bf16(f2, f3) };
            *(i32x2*)&base[col * COLBYTES + off] = p;
        }
        if (hasB) {
            #pragma unroll
            for (int j = 0; j < 4; ++j) {
                const float f0 = (j == 0) ? b0.x : (j == 1) ? b0.y : (j == 2) ? b0.z : b0.w;
                const float f1 = (j == 0) ? b1.x : (j == 1) ? b1.y : (j == 2) ? b1.z : b1.w;
                const float f2 = (j == 0) ? b2.x : (j == 1) ? b2.y : (j == 2) ? b2.z : b2.w;
                const float f3 = (j == 0) ? b3.x : (j == 1) ? b3.y : (j == 2) ? b3.z : b3.w;
                const int col = 4 * cgB + j;
                const int off = (8 * rgB + 16 * ((5 * cgB + j) & 15)) & 255;
                i32x2 p = { pk_bf16(f0, f1), pk_bf16(f2, f3) };
                *(i32x2*)&base[col * COLBYTES + off] = p;
            }
        }
    };

    // prologue: stage 0 staged; A stages 1,2 and B stage 1 in flight
    load_a(A[0], 0);
    load_b(0);
    load_a(A[1], 1);           // issue ahead of write_stage (independent regs)
    write_stage(A[0], 0);      // waits only its own loads (counted vmcnt)
    load_b(1);
    load_a(A[0], 2);           // A[0] free after write_stage(0)
    bar_lgkm();

    #pragma unroll
    for (int s = 0; s < NSTAGES; ++s) {
        {   // compute on buf s&1: 3 frag loads + 6 MFMAs (frag = both A and B operand)
            const char* base = tb[s & 1];
            const bf16x8 f0 = *(const bf16x8*)&base[(0 * 16 + fcol) * COLBYTES + fo0];
            const bf16x8 f1 = *(const bf16x8*)&base[(1 * 16 + fcol) * COLBYTES + fo1];
            const bf16x8 f2 = *(const bf16x8*)&base[(2 * 16 + fcol) * COLBYTES + fo2];
            acc[0] = __builtin_amdgcn_mfma_f32_16x16x32_bf16(f0, f0, acc[0], 0, 0, 0);
            acc[1] = __builtin_amdgcn_mfma_f32_16x16x32_bf16(f1, f0, acc[1], 0, 0, 0);
            acc[2] = __builtin_amdgcn_mfma_f32_16x16x32_bf16(f1, f1, acc[2], 0, 0, 0);
            acc[3] = __builtin_amdgcn_mfma_f32_16x16x32_bf16(f2, f0, acc[3], 0, 0, 0);
            acc[4] = __builtin_amdgcn_mfma_f32_16x16x32_bf16(f2, f1, acc[4], 0, 0, 0);
            acc[5] = __builtin_amdgcn_mfma_f32_16x16x32_bf16(f2, f2, acc[5], 0, 0, 0);
        }
        if (s + 1 < NSTAGES) write_stage(A[(s + 1) & 1], (s + 1) & 1);  // stage s+1 -> other buf
        if (s + 3 < NSTAGES) load_a(A[(s + 1) & 1], s + 3);             // refill freed A set
        if (s + 2 < NSTAGES) load_b(s + 2);
        bar_lgkm();  // LDS-only barrier: prefetch loads stay in flight
    }

    // single-barrier cross-wave merge: dump accs into tb scratch, one barrier,
    // then 1536 coalesced sums+stores (lower-tri tiles only).
    // C/D layout col=lane&15, row=(lane>>4)*4+reg [m89/m91].
    // part layout: [wave][t6][row 0..15][col 0..15] floats = 24576 B = sizeof(tb).
    float* part = (float*)tb;
    #pragma unroll
    for (int t6 = 0; t6 < 6; ++t6) {
        #pragma unroll
        for (int r = 0; r < 4; ++r)
            part[wave * NTILE + t6 * 256 + (fq * 4 + r) * 16 + fcol] = acc[t6][r];
    }
    bar_lgkm();

    // P[block][1536] identity-indexed: e = t6*256 + row*16 + col. Pure coalesced.
    float* __restrict__ Pb = P + (size_t)blockIdx.x * NTILE;
    #pragma unroll
    for (int i = 0; i < 6; ++i) {
        const int e = tid + 256 * i;
        Pb[e] = part[e] + part[NTILE + e] + part[2 * NTILE + e] + part[3 * NTILE + e];
    }
}

// Sum the 128 chunk-partials per (batch, tile-entry), apply mask, reduce to out[0].
// Grid: BATCHES * 24 = 192 blocks; block owns 64 entries, 4-way chunk split.
__global__ __launch_bounds__(256) void reduce_finish(const float* __restrict__ P,
                                                     float* __restrict__ out) {
    const int tid = threadIdx.x;
    const int b = blockIdx.x / 24;
    const int e0 = (blockIdx.x % 24) * 64;
    const int cs = tid / 64;            // chunk strip 0..3
    const int el = tid % 64;            // entry within strip
    const int e = e0 + el;              // 0..1535

    float g = 0.f;
    const float* base = P + (size_t)b * CHUNKS * NTILE + e;
    #pragma unroll 4
    for (int c = cs; c < CHUNKS; c += 4) g += base[(size_t)c * NTILE];  // 256B/wave coalesced

    __shared__ float part[4][64];
    part[cs][el] = g;
    __syncthreads();

    float contrib = 0.f;
    if (tid < 64) {
        g = part[0][el] + part[1][el] + part[2][el] + part[3][el];
        // e -> (t6, row, col) -> (gi, gj) in the 48x48 Gram
        const int t6 = e >> 8;
        const int t = (t6 >= 3) ? 2 : (t6 >= 1) ? 1 : 0;
        const int u = t6 - ((t * (t + 1)) >> 1);
        const int gi = 16 * t + ((e >> 4) & 15);
        const int gj = 16 * u + (e & 15);
        if (gi < (DE + SV) && gj <= gi) {
            const float w = (gi == gj) ? 1.f : 2.f;                   // off-diag counted twice
            const float sgn = ((gi < DE) == (gj < DE)) ? 1.f : -1.f;  // EE/VV +, mixed -
            contrib = w * sgn * g * g;
        }
        #pragma unroll
        for (int o = 32; o > 0; o >>= 1) contrib += __shfl_down(contrib, o, 64);
        if (tid == 0)
            atomicAdd(out, contrib * (1.f / ((float)BATCHES * (float)NROWS)));  // 192 atomics
    }
}

extern "C" void kernel_launch(void* const* d_in, const int* in_sizes, int n_in,
                              void* d_out, int out_size, void* d_ws, size_t ws_size,
                              hipStream_t stream) {
    const float* E = (const float*)d_in[0];   // embeddings (B,F,T,D) fp32
    const float* V = (const float*)d_in[1];   // assignments (B,F,T,S) fp32
    float* P = (float*)d_ws;                  // 1024 x 1536 fp32 partial tiles (6.3 MB)

    // no hipMemsetAsync: gram_kernel block 0 zeroes out[0] (stream-ordered
    // before reduce_finish's atomicAdds)
    gram_kernel<<<BATCHES * CHUNKS, 256, 0, stream>>>(E, V, P, (float*)d_out);
    reduce_finish<<<BATCHES * 24, 256, 0, stream>>>(P, (float*)d_out);
}